// Round 6
// baseline (146.172 us; speedup 1.0000x reference)
//
#include <hip/hip_runtime.h>
#include <hip/hip_bf16.h>

// GAT layer, B=4, N=4096, F_in=128, F_out=64.
// out_i = sum_j adj_ij * exp(leaky(s2_i+s1_j)) * Wh_j
//         / ( sum_j adj_ij*exp(..) + 1e-9 * sum_j exp(..) )
// softmax max-subtraction cancels exactly; scores are O(8) so bare exp2 safe.
// s1/s2 stored pre-scaled by log2(e).
//
// R6: K-split occupancy fix. 4096 independent waves (16-row tile x 1024-j
// split), no barriers, P built in MFMA A-fragment registers (validated R5),
// partials (16x64 num + S/Z) to ws, tiny combine kernel. 12 waves/CU ->
// ~48KB in flight per CU >> 9.2KB Little's-law minimum for 6.3 TB/s.

typedef __attribute__((ext_vector_type(8))) short bf16x8;
typedef __attribute__((ext_vector_type(4))) float f32x4;
typedef __attribute__((ext_vector_type(4))) unsigned int u32x4;

#define LOG2E 1.4426950408889634f

__device__ __forceinline__ unsigned short f2bf(float x) {
  union { float f; unsigned int u; } c; c.f = x;
  unsigned int r = c.u + 0x7fffu + ((c.u >> 16) & 1u);  // RNE
  return (unsigned short)(r >> 16);
}
__device__ __forceinline__ unsigned int pk2(float lo, float hi) {
  float2 f2; f2.x = lo; f2.y = hi;
  union { __hip_bfloat162 b; unsigned int u; } c;
  c.b = __float22bfloat162_rn(f2);   // v_cvt_pk_bf16_f32
  return c.u;
}
__device__ __forceinline__ bf16x8 u2b(u32x4 v) {
  union { u32x4 u; bf16x8 b; } c; c.u = v; return c.b;
}

// ---------------- K1: Wh = h @ W (f32); WhT bf16 [b][64col][4096k];
//                  s1 = Wh a1 * log2e, s2 = Wh a2 * log2e
__global__ __launch_bounds__(256) void k_wh(
    const float* __restrict__ h, const float* __restrict__ W, const float* __restrict__ a,
    unsigned short* __restrict__ wt, float* __restrict__ s1, float* __restrict__ s2) {
  __shared__ float hs[32][130];
  const int t = threadIdx.x;
  const int b = blockIdx.x >> 7;
  const int row0 = (blockIdx.x & 127) << 5;

  #pragma unroll
  for (int it = 0; it < 4; ++it) {
    int flat = it * 256 + t;
    int r = flat >> 5, q = flat & 31;
    const float4 v = *(const float4*)(h + ((size_t)(b * 4096 + row0 + r)) * 128 + 4 * q);
    hs[r][4*q+0] = v.x; hs[r][4*q+1] = v.y; hs[r][4*q+2] = v.z; hs[r][4*q+3] = v.w;
  }
  __syncthreads();

  const int rg = t >> 4, cg = t & 15;
  float acc[2][4] = {};
  for (int k = 0; k < 128; ++k) {
    float4 wv = *(const float4*)(W + k * 64 + 4 * cg);
    #pragma unroll
    for (int i = 0; i < 2; ++i) {
      float hv = hs[2*rg + i][k];
      acc[i][0] = fmaf(hv, wv.x, acc[i][0]);
      acc[i][1] = fmaf(hv, wv.y, acc[i][1]);
      acc[i][2] = fmaf(hv, wv.z, acc[i][2]);
      acc[i][3] = fmaf(hv, wv.w, acc[i][3]);
    }
  }
  __syncthreads();

  float (*WhF)[68] = (float(*)[68])hs;
  #pragma unroll
  for (int i = 0; i < 2; ++i)
    #pragma unroll
    for (int j = 0; j < 4; ++j)
      WhF[2*rg + i][4*cg + j] = acc[i][j];
  __syncthreads();

  if (t < 32) {
    float x1 = 0.f, x2 = 0.f;
    #pragma unroll 8
    for (int c = 0; c < 64; ++c) {
      float v = WhF[t][c];
      x1 = fmaf(v, a[c], x1);
      x2 = fmaf(v, a[64 + c], x2);
    }
    s1[b * 4096 + row0 + t] = x1 * LOG2E;
    s2[b * 4096 + row0 + t] = x2 * LOG2E;
  }

  const int col = t >> 2, sub = t & 3;
  unsigned int uh[4];
  #pragma unroll
  for (int r = 0; r < 4; ++r) {
    unsigned short h0 = f2bf(WhF[8*sub + 2*r][col]);
    unsigned short h1 = f2bf(WhF[8*sub + 2*r + 1][col]);
    uh[r] = (unsigned)h0 | ((unsigned)h1 << 16);
  }
  size_t base = ((size_t)(b * 64 + col)) * 4096 + row0 + 8 * sub;
  *(uint4*)(wt + base) = make_uint4(uh[0], uh[1], uh[2], uh[3]);
}

// ---------------- K3: partial num/S/Z per (16-row tile, 1024-j split).
// 4096 blocks x 64 threads, 1 wave each, zero LDS, zero barriers.
// Lane l: P row = l&15, k-chunk 8*(l>>4); B col = (l&15)+16cg.
__global__ __launch_bounds__(64, 3) void k_main(
    const float* __restrict__ adj, const unsigned short* __restrict__ wt,
    const float* __restrict__ s1, const float* __restrict__ s2,
    float* __restrict__ part) {
  const int l = threadIdx.x;
  const int blk = blockIdx.x;
  // XCD mapping: blk&7 = XCD; one batch b per XCD pair (wt slice L2-resident)
  const int xcd = blk & 7;
  const int b = xcd >> 1;
  const int u = (blk >> 3) | ((xcd & 1) << 9);   // 0..1023 per b, bijective
  const int t = u & 255;                          // tile (16 rows)
  const int p = u >> 8;                           // k-split 0..3
  const int row0 = t << 4;
  const int lr = l & 15, g = l >> 4;
  const int kbase = p << 10;

  const float* adjBase = adj + ((size_t)(b * 4096 + row0 + lr)) * 4096 + kbase + 8 * g;
  const float* s1Base = s1 + b * 4096 + kbase + 8 * g;
  const float s2v = s2[b * 4096 + row0 + lr];
  const unsigned short* wtB = wt + ((size_t)(b * 64 + lr)) * 4096 + kbase + 8 * g;

  float z = 0.f, sa = 0.f;
  f32x4 acc[4] = {{0.f,0.f,0.f,0.f},{0.f,0.f,0.f,0.f},{0.f,0.f,0.f,0.f},{0.f,0.f,0.f,0.f}};

#define LOADA(av, sv, ks) do {                                                \
    const int ko = ((ks) & 15) << 6;                                          \
    av[0] = __builtin_nontemporal_load((const f32x4*)(adjBase + ko));         \
    av[1] = __builtin_nontemporal_load((const f32x4*)(adjBase + ko + 4));     \
    av[2] = __builtin_nontemporal_load((const f32x4*)(adjBase + ko + 32));    \
    av[3] = __builtin_nontemporal_load((const f32x4*)(adjBase + ko + 36));    \
    sv[0] = *(const f32x4*)(s1Base + ko);                                     \
    sv[1] = *(const f32x4*)(s1Base + ko + 4);                                 \
    sv[2] = *(const f32x4*)(s1Base + ko + 32);                                \
    sv[3] = *(const f32x4*)(s1Base + ko + 36);                                \
  } while (0)

#define LOADB(bv, ks) do {                                                    \
    const int ko = (ks) << 6;                                                 \
    _Pragma("unroll")                                                         \
    for (int cg = 0; cg < 4; ++cg) {                                          \
      bv[2*cg]   = *(const u32x4*)(wtB + cg * 65536 + ko);                    \
      bv[2*cg+1] = *(const u32x4*)(wtB + cg * 65536 + ko + 32);               \
    }                                                                         \
  } while (0)

#define STEPX(av, sv, bv) do {                                                \
    bf16x8 fr0, fr1;                                                          \
    _Pragma("unroll")                                                         \
    for (int kk = 0; kk < 2; ++kk) {                                          \
      unsigned int pk[4];                                                     \
      _Pragma("unroll")                                                       \
      for (int q = 0; q < 4; ++q) {                                           \
        float e0 = s2v + sv[2*kk + (q>>1)][(q&1)*2 + 0];                      \
        float e1 = s2v + sv[2*kk + (q>>1)][(q&1)*2 + 1];                      \
        e0 = fmaxf(e0, 0.2f*e0); e1 = fmaxf(e1, 0.2f*e1);                     \
        float p0 = exp2f(e0), p1 = exp2f(e1);                                 \
        float w0 = av[2*kk + (q>>1)][(q&1)*2 + 0] * p0;                       \
        float w1 = av[2*kk + (q>>1)][(q&1)*2 + 1] * p1;                       \
        z += p0 + p1; sa += w0 + w1;                                          \
        pk[q] = pk2(w0, w1);                                                  \
      }                                                                       \
      union { unsigned int s[4]; u32x4 v; } fu;                               \
      fu.s[0] = pk[0]; fu.s[1] = pk[1]; fu.s[2] = pk[2]; fu.s[3] = pk[3];     \
      if (kk == 0) fr0 = u2b(fu.v); else fr1 = u2b(fu.v);                     \
    }                                                                         \
    _Pragma("unroll")                                                         \
    for (int cg = 0; cg < 4; ++cg) {                                          \
      acc[cg] = __builtin_amdgcn_mfma_f32_16x16x32_bf16(fr0, u2b(bv[2*cg]),   \
                                                        acc[cg], 0, 0, 0);    \
      acc[cg] = __builtin_amdgcn_mfma_f32_16x16x32_bf16(fr1, u2b(bv[2*cg+1]), \
                                                        acc[cg], 0, 0, 0);    \
    }                                                                         \
  } while (0)

  f32x4 aA[4], sAv[4]; f32x4 aB[4], sBv[4];
  u32x4 bv[8];

  LOADA(aA, sAv, 0);
  for (int it = 0; it < 8; ++it) {
    LOADA(aB, sBv, 2*it + 1);     // HBM prefetch, in flight over STEPX A
    LOADB(bv, 2*it);              // L2 hit, covered by STEPX's VALU
    STEPX(aA, sAv, bv);
    LOADA(aA, sAv, 2*it + 2);     // wraps to ko=0 at the end (harmless)
    LOADB(bv, 2*it + 1);
    STEPX(aB, sBv, bv);
  }

  // reduce z/sa over the 4 lane-groups sharing a row
  z += __shfl_xor(z, 16);   z += __shfl_xor(z, 32);
  sa += __shfl_xor(sa, 16); sa += __shfl_xor(sa, 32);

  // write partial: [1024] num (16x64 row-major) | [16] S | [16] Z
  float* pb = part + ((size_t)((b * 256 + t) * 4 + p)) * 1056;
  #pragma unroll
  for (int reg = 0; reg < 4; ++reg) {
    const int row = 4 * g + reg;
    #pragma unroll
    for (int cg = 0; cg < 4; ++cg)
      pb[row * 64 + 16 * cg + lr] = acc[cg][reg];
  }
  if (l < 16) {
    pb[1024 + l] = sa;   // lane l holds row l totals after the xor-reduce
    pb[1040 + l] = z;
  }
}

// ---------------- K4: combine 4 partials, scale, write out
__global__ __launch_bounds__(256) void k_final(
    const float* __restrict__ part, float* __restrict__ out) {
  const int tid = threadIdx.x;
  const int l = tid & 63, q = tid >> 6;
  const int tt = blockIdx.x;              // 0..1023 = b*256 + t
  const float* pb = part + (size_t)tt * 4224;
  __shared__ float invs[16];
  if (tid < 16) {
    float S = pb[1024+tid] + pb[1056+1024+tid] + pb[2112+1024+tid] + pb[3168+1024+tid];
    float Z = pb[1040+tid] + pb[1056+1040+tid] + pb[2112+1040+tid] + pb[3168+1040+tid];
    invs[tid] = 1.0f / (S + 1e-9f * Z);
  }
  __syncthreads();
  #pragma unroll
  for (int rr = 0; rr < 4; ++rr) {
    const int r = q * 4 + rr;
    const int o = r * 64 + l;
    float v = (pb[o] + pb[1056 + o]) + (pb[2112 + o] + pb[3168 + o]);
    out[((size_t)(tt * 16 + r)) * 64 + l] = v * invs[r];
  }
}

extern "C" void kernel_launch(void* const* d_in, const int* in_sizes, int n_in,
                              void* d_out, int out_size, void* d_ws, size_t ws_size,
                              hipStream_t stream) {
  const float* h   = (const float*)d_in[0];
  const float* adj = (const float*)d_in[1];
  const float* W   = (const float*)d_in[2];
  const float* a   = (const float*)d_in[3];
  float* out = (float*)d_out;

  // ws layout: WhT (2MB bf16) | s1 (64KB) | s2 (64KB) | partials (17.3MB)
  unsigned short* wt = (unsigned short*)d_ws;
  float* s1 = (float*)(wt + (size_t)4 * 64 * 4096);
  float* s2 = s1 + 16384;
  float* part = s2 + 16384;

  k_wh   <<<512, 256, 0, stream>>>(h, W, a, wt, s1, s2);
  k_main <<<4096, 64, 0, stream>>>(adj, wt, s1, s2, part);
  k_final<<<1024, 256, 0, stream>>>(part, out);
}

// Round 7
// 76.677 us; speedup vs baseline: 1.9063x; 1.9063x over previous
//
#include <hip/hip_runtime.h>
#include <hip/hip_bf16.h>

// GAT layer, B=4, N=4096, F_in=128, F_out=64.
// out_i = sum_j adj_ij * exp(leaky(s2_i+s1_j)) * Wh_j / sum_j adj_ij*exp(..)
// (softmax normalizer cancels; eps*Z term is 2e-9 relative -> dropped;
//  scores O(8) so bare exp2 is safe; s1/s2 pre-scaled by log2 e.)
//
// R7: R2 skeleton + page-local adj loads (1KB contiguous per instruction,
// one row per wave-instr), in-register P-build -> XOR-swizzled LDS P tile,
// K-step 256 (1 barrier/step, 16 barriers total), hi-only bf16 B from L2
// (8 x b128 per wave per step), v_exp_f32 + cvt_pk packing, no Z.

typedef __attribute__((ext_vector_type(8))) short bf16x8;
typedef __attribute__((ext_vector_type(4))) float f32x4;
typedef __attribute__((ext_vector_type(4))) unsigned int u32x4;

#define LOG2E 1.4426950408889634f

__device__ __forceinline__ unsigned int pk2(float lo, float hi) {
  float2 f2; f2.x = lo; f2.y = hi;
  union { __hip_bfloat162 b; unsigned int u; } c;
  c.b = __float22bfloat162_rn(f2);
  return c.u;
}
__device__ __forceinline__ bf16x8 u2b(u32x4 v) {
  union { u32x4 u; bf16x8 b; } c; c.u = v; return c.b;
}
__device__ __forceinline__ float vexp2_(float x) {
  float r; asm("v_exp_f32 %0, %1" : "=v"(r) : "v"(x)); return r;
}

// ---------------- K1: Wh = h @ W (f32); WhT bf16 [b][64col][4096k];
//                  s1 = Wh a1 * log2e, s2 = Wh a2 * log2e
__global__ __launch_bounds__(256) void k_wh(
    const float* __restrict__ h, const float* __restrict__ W, const float* __restrict__ a,
    unsigned short* __restrict__ wt, float* __restrict__ s1, float* __restrict__ s2) {
  __shared__ float hs[32][130];
  const int t = threadIdx.x;
  const int b = blockIdx.x >> 7;
  const int row0 = (blockIdx.x & 127) << 5;

  #pragma unroll
  for (int it = 0; it < 4; ++it) {
    int flat = it * 256 + t;
    int r = flat >> 5, q = flat & 31;
    const float4 v = *(const float4*)(h + ((size_t)(b * 4096 + row0 + r)) * 128 + 4 * q);
    hs[r][4*q+0] = v.x; hs[r][4*q+1] = v.y; hs[r][4*q+2] = v.z; hs[r][4*q+3] = v.w;
  }
  __syncthreads();

  const int rg = t >> 4, cg = t & 15;
  float acc[2][4] = {};
  for (int k = 0; k < 128; ++k) {
    float4 wv = *(const float4*)(W + k * 64 + 4 * cg);
    #pragma unroll
    for (int i = 0; i < 2; ++i) {
      float hv = hs[2*rg + i][k];
      acc[i][0] = fmaf(hv, wv.x, acc[i][0]);
      acc[i][1] = fmaf(hv, wv.y, acc[i][1]);
      acc[i][2] = fmaf(hv, wv.z, acc[i][2]);
      acc[i][3] = fmaf(hv, wv.w, acc[i][3]);
    }
  }
  __syncthreads();

  float (*WhF)[68] = (float(*)[68])hs;
  #pragma unroll
  for (int i = 0; i < 2; ++i)
    #pragma unroll
    for (int j = 0; j < 4; ++j)
      WhF[2*rg + i][4*cg + j] = acc[i][j];
  __syncthreads();

  if (t < 32) {
    float x1 = 0.f, x2 = 0.f;
    #pragma unroll 8
    for (int c = 0; c < 64; ++c) {
      float v = WhF[t][c];
      x1 = fmaf(v, a[c], x1);
      x2 = fmaf(v, a[64 + c], x2);
    }
    s1[b * 4096 + row0 + t] = x1 * LOG2E;
    s2[b * 4096 + row0 + t] = x2 * LOG2E;
  }

  const int col = t >> 2, sub = t & 3;
  unsigned int uh[4];
  #pragma unroll
  for (int r = 0; r < 4; ++r)
    uh[r] = pk2(WhF[8*sub + 2*r][col], WhF[8*sub + 2*r + 1][col]);
  size_t base = ((size_t)(b * 64 + col)) * 4096 + row0 + 8 * sub;
  *(uint4*)(wt + base) = make_uint4(uh[0], uh[1], uh[2], uh[3]);
}

// ---------------- K3: out = P @ Wh, K-step 256.
// 512 blocks x 256 thr (4 waves, 2 blocks/CU). Wave w owns adj rows 8w..8w+7
// (each row-chunk = ONE 1KB-contiguous load instr) and output cols 16w..16w+16
// (B-frags private, no duplication). P: registers -> swizzled LDS -> A-frags.
__global__ __launch_bounds__(256, 2) void k_main(
    const float* __restrict__ adj, const unsigned short* __restrict__ wt,
    const float* __restrict__ s1, const float* __restrict__ s2,
    float* __restrict__ out) {
  __shared__ unsigned short Pws[2][8192];   // 2 x (32 rows x 512B, XOR-swizzled)
  __shared__ float Ss[32];

  const int t = threadIdx.x;
  const int blk = blockIdx.x;
  const int xcd = blk & 7;                   // default round-robin XCD id
  const int b = xcd >> 1;                    // one batch per XCD pair: wt L2-resident
  const int tile = (blk >> 3) + ((xcd & 1) << 6);   // 0..127 bijective per b
  const int row0 = tile << 5;
  const int l = t & 63, w = t >> 6;
  const int lr = l & 15, g = l >> 4;

  const float* adjW = adj + ((size_t)(b * 4096 + row0 + 8 * w)) * 4096 + 4 * l;
  const float* s1W  = s1 + b * 4096 + 4 * l;
  const unsigned short* wtB = wt + ((size_t)(b * 64 + 16 * w + lr)) * 4096 + 8 * g;

  float s2r[8];
  #pragma unroll
  for (int r = 0; r < 8; ++r) s2r[r] = s2[b * 4096 + row0 + 8 * w + r];

  float sar[8] = {0.f,0.f,0.f,0.f,0.f,0.f,0.f,0.f};
  f32x4 acc0 = {0.f,0.f,0.f,0.f}, acc1 = {0.f,0.f,0.f,0.f};

  f32x4 aX[8], aY[8], sX, sY;
  u32x4 bv[8];

#define LOADADJ(av, sv, ks) do {                                              \
    const int ko = ((ks) & 15) << 8;                                          \
    _Pragma("unroll")                                                         \
    for (int r = 0; r < 8; ++r)                                               \
      av[r] = __builtin_nontemporal_load(                                     \
          (const f32x4*)(adjW + (size_t)r * 4096 + ko));                      \
    sv = *(const f32x4*)(s1W + ko);                                           \
  } while (0)

#define LOADB(ks) do {                                                        \
    const int ko = ((ks) & 15) << 8;                                          \
    _Pragma("unroll")                                                         \
    for (int kk = 0; kk < 8; ++kk)                                            \
      bv[kk] = *(const u32x4*)(wtB + ko + 32 * kk);                           \
  } while (0)

  // lane l holds rows 8w..8w+7, cols [4l,4l+4). Write 8B to swizzled P row:
  // element col c of row r8 lives at short-offset c ^ ((r8&7)<<3).
#define PBUILD(av, sv, buf) do {                                              \
    unsigned short* Pd = &Pws[buf][0];                                        \
    _Pragma("unroll")                                                         \
    for (int r = 0; r < 8; ++r) {                                             \
      float e0 = s2r[r] + sv[0], e1 = s2r[r] + sv[1];                         \
      float e2 = s2r[r] + sv[2], e3 = s2r[r] + sv[3];                         \
      e0 = fmaxf(e0, 0.2f * e0); e1 = fmaxf(e1, 0.2f * e1);                   \
      e2 = fmaxf(e2, 0.2f * e2); e3 = fmaxf(e3, 0.2f * e3);                   \
      float p0 = vexp2_(e0), p1 = vexp2_(e1);                                 \
      float p2 = vexp2_(e2), p3 = vexp2_(e3);                                 \
      float w0 = av[r][0] * p0, w1 = av[r][1] * p1;                           \
      float w2 = av[r][2] * p2, w3 = av[r][3] * p3;                           \
      sar[r] += (w0 + w1) + (w2 + w3);                                        \
      uint2 pk; pk.x = pk2(w0, w1); pk.y = pk2(w2, w3);                       \
      *(uint2*)(Pd + (8 * w + r) * 256 + ((4 * l) ^ (r << 3))) = pk;          \
    }                                                                         \
  } while (0)

#define SYNC() do {                                                           \
    asm volatile("s_waitcnt lgkmcnt(0)" ::: "memory");                        \
    __builtin_amdgcn_sched_barrier(0);                                        \
    __builtin_amdgcn_s_barrier();                                             \
    __builtin_amdgcn_sched_barrier(0);                                        \
  } while (0)

#define MFMAP(buf) do {                                                       \
    const unsigned short* Pr = &Pws[buf][0];                                  \
    _Pragma("unroll")                                                         \
    for (int kk = 0; kk < 8; ++kk) {                                          \
      const int koff = (8 * g + 32 * kk) ^ ((lr & 7) << 3);                   \
      bf16x8 a0 = *(const bf16x8*)(Pr + lr * 256 + koff);                     \
      bf16x8 a1 = *(const bf16x8*)(Pr + (16 + lr) * 256 + koff);              \
      acc0 = __builtin_amdgcn_mfma_f32_16x16x32_bf16(a0, u2b(bv[kk]), acc0, 0, 0, 0); \
      acc1 = __builtin_amdgcn_mfma_f32_16x16x32_bf16(a1, u2b(bv[kk]), acc1, 0, 0, 0); \
    }                                                                         \
  } while (0)

  LOADADJ(aX, sX, 0);
  LOADADJ(aY, sY, 1);
  LOADB(0);

  for (int it = 0; it < 8; ++it) {
    PBUILD(aX, sX, 0);
    LOADADJ(aX, sX, 2 * it + 2);   // depth-2 HBM prefetch (wraps harmlessly)
    SYNC();                        // lgkm only: HBM prefetch stays in flight
    MFMAP(0);
    LOADB(2 * it + 1);             // B(s+1): in flight across next P-build

    PBUILD(aY, sY, 1);
    LOADADJ(aY, sY, 2 * it + 3);
    SYNC();
    MFMAP(1);
    LOADB(2 * it + 2);
  }

  // S row sums: full-wave butterfly per row, lane 0 publishes
  #pragma unroll
  for (int r = 0; r < 8; ++r) {
    float v = sar[r];
    #pragma unroll
    for (int m = 1; m < 64; m <<= 1) v += __shfl_xor(v, m);
    sar[r] = v;
  }
  if (l == 0) {
    #pragma unroll
    for (int r = 0; r < 8; ++r) Ss[8 * w + r] = sar[r];
  }
  __syncthreads();

  // epilogue: out = acc / S ; C layout col=lr, row=4g+reg (+16 for acc1)
  #pragma unroll
  for (int reg = 0; reg < 4; ++reg) {
    const int r0 = 4 * g + reg, r1 = 16 + 4 * g + reg;
    const float i0 = 1.0f / Ss[r0], i1 = 1.0f / Ss[r1];
    const size_t ob = ((size_t)(b * 4096 + row0 + r0)) * 64 + 16 * w + lr;
    out[ob] = acc0[reg] * i0;
    out[ob + (size_t)16 * 64] = acc1[reg] * i1;
  }
}

extern "C" void kernel_launch(void* const* d_in, const int* in_sizes, int n_in,
                              void* d_out, int out_size, void* d_ws, size_t ws_size,
                              hipStream_t stream) {
  const float* h   = (const float*)d_in[0];
  const float* adj = (const float*)d_in[1];
  const float* W   = (const float*)d_in[2];
  const float* a   = (const float*)d_in[3];
  float* out = (float*)d_out;

  // ws layout: WhT (2MB bf16) | s1 (64KB) | s2 (64KB)
  unsigned short* wt = (unsigned short*)d_ws;
  float* s1 = (float*)(wt + (size_t)4 * 64 * 4096);
  float* s2 = s1 + 16384;

  k_wh  <<<512, 256, 0, stream>>>(h, W, a, wt, s1, s2);
  k_main<<<512, 256, 0, stream>>>(adj, wt, s1, s2, out);
}

// Round 8
// 70.120 us; speedup vs baseline: 2.0846x; 1.0935x over previous
//
#include <hip/hip_runtime.h>
#include <hip/hip_bf16.h>

// GAT layer, B=4, N=4096, F_in=128, F_out=64.
// out_i = sum_j adj_ij * exp(leaky(s2_i+s1_j)) * Wh_j / sum_j adj_ij*exp(..)
// (softmax normalizer cancels; eps*Z term is 2e-9 relative -> dropped;
//  scores O(8) so bare exp2 is safe; s1/s2 pre-scaled by log2 e.)
//
// R8 = R7 with two isolated changes:
//  1. k_main: adj loads PLAIN (was nontemporal) — nt suspected of degrading
//     read burst efficiency (~4 TB/s observed vs 7 TB/s plain-write fills).
//  2. k_wh: W staged in LDS once (was 128 L1 re-reads/thread through the
//     64 B/cyc L1 port; LDS pipe is 128 B/cyc, cg/cg+8 2-way conflict free).

typedef __attribute__((ext_vector_type(8))) short bf16x8;
typedef __attribute__((ext_vector_type(4))) float f32x4;
typedef __attribute__((ext_vector_type(4))) unsigned int u32x4;

#define LOG2E 1.4426950408889634f

__device__ __forceinline__ unsigned int pk2(float lo, float hi) {
  float2 f2; f2.x = lo; f2.y = hi;
  union { __hip_bfloat162 b; unsigned int u; } c;
  c.b = __float22bfloat162_rn(f2);
  return c.u;
}
__device__ __forceinline__ bf16x8 u2b(u32x4 v) {
  union { u32x4 u; bf16x8 b; } c; c.u = v; return c.b;
}
__device__ __forceinline__ float vexp2_(float x) {
  float r; asm("v_exp_f32 %0, %1" : "=v"(r) : "v"(x)); return r;
}

// ---------------- K1: Wh = h @ W (f32); WhT bf16 [b][64col][4096k];
//                  s1 = Wh a1 * log2e, s2 = Wh a2 * log2e
__global__ __launch_bounds__(256) void k_wh(
    const float* __restrict__ h, const float* __restrict__ W, const float* __restrict__ a,
    unsigned short* __restrict__ wt, float* __restrict__ s1, float* __restrict__ s2) {
  __shared__ float hs[32][130];
  __shared__ float Ws[128 * 64];
  const int t = threadIdx.x;
  const int b = blockIdx.x >> 7;
  const int row0 = (blockIdx.x & 127) << 5;

  // stage W (32KB) into LDS, once
  #pragma unroll
  for (int it = 0; it < 8; ++it) {
    const int fidx = it * 256 + t;
    ((float4*)Ws)[fidx] = ((const float4*)W)[fidx];
  }
  // stage h tile: 32 rows x 128 f32
  #pragma unroll
  for (int it = 0; it < 4; ++it) {
    int flat = it * 256 + t;
    int r = flat >> 5, q = flat & 31;
    const float4 v = *(const float4*)(h + ((size_t)(b * 4096 + row0 + r)) * 128 + 4 * q);
    hs[r][4*q+0] = v.x; hs[r][4*q+1] = v.y; hs[r][4*q+2] = v.z; hs[r][4*q+3] = v.w;
  }
  __syncthreads();

  const int rg = t >> 4, cg = t & 15;
  float acc[2][4] = {};
  for (int k = 0; k < 128; ++k) {
    float4 wv = ((const float4*)Ws)[k * 16 + cg];   // LDS b128, 2-way max
    #pragma unroll
    for (int i = 0; i < 2; ++i) {
      float hv = hs[2*rg + i][k];
      acc[i][0] = fmaf(hv, wv.x, acc[i][0]);
      acc[i][1] = fmaf(hv, wv.y, acc[i][1]);
      acc[i][2] = fmaf(hv, wv.z, acc[i][2]);
      acc[i][3] = fmaf(hv, wv.w, acc[i][3]);
    }
  }
  __syncthreads();

  float (*WhF)[68] = (float(*)[68])hs;
  #pragma unroll
  for (int i = 0; i < 2; ++i)
    #pragma unroll
    for (int j = 0; j < 4; ++j)
      WhF[2*rg + i][4*cg + j] = acc[i][j];
  __syncthreads();

  if (t < 32) {
    float x1 = 0.f, x2 = 0.f;
    #pragma unroll 8
    for (int c = 0; c < 64; ++c) {
      float v = WhF[t][c];
      x1 = fmaf(v, a[c], x1);
      x2 = fmaf(v, a[64 + c], x2);
    }
    s1[b * 4096 + row0 + t] = x1 * LOG2E;
    s2[b * 4096 + row0 + t] = x2 * LOG2E;
  }

  const int col = t >> 2, sub = t & 3;
  unsigned int uh[4];
  #pragma unroll
  for (int r = 0; r < 4; ++r)
    uh[r] = pk2(WhF[8*sub + 2*r][col], WhF[8*sub + 2*r + 1][col]);
  size_t base = ((size_t)(b * 64 + col)) * 4096 + row0 + 8 * sub;
  *(uint4*)(wt + base) = make_uint4(uh[0], uh[1], uh[2], uh[3]);
}

// ---------------- K3: out = P @ Wh, K-step 256.
// 512 blocks x 256 thr (4 waves, 2 blocks/CU). Wave w owns adj rows 8w..8w+7
// (each row-chunk = ONE 1KB-contiguous load instr) and output cols 16w..16w+16
// (B-frags private, no duplication). P: registers -> swizzled LDS -> A-frags.
__global__ __launch_bounds__(256, 2) void k_main(
    const float* __restrict__ adj, const unsigned short* __restrict__ wt,
    const float* __restrict__ s1, const float* __restrict__ s2,
    float* __restrict__ out) {
  __shared__ unsigned short Pws[2][8192];   // 2 x (32 rows x 512B, XOR-swizzled)
  __shared__ float Ss[32];

  const int t = threadIdx.x;
  const int blk = blockIdx.x;
  const int xcd = blk & 7;                   // default round-robin XCD id
  const int b = xcd >> 1;                    // one batch per XCD pair: wt L2-resident
  const int tile = (blk >> 3) + ((xcd & 1) << 6);   // 0..127 bijective per b
  const int row0 = tile << 5;
  const int l = t & 63, w = t >> 6;
  const int lr = l & 15, g = l >> 4;

  const float* adjW = adj + ((size_t)(b * 4096 + row0 + 8 * w)) * 4096 + 4 * l;
  const float* s1W  = s1 + b * 4096 + 4 * l;
  const unsigned short* wtB = wt + ((size_t)(b * 64 + 16 * w + lr)) * 4096 + 8 * g;

  float s2r[8];
  #pragma unroll
  for (int r = 0; r < 8; ++r) s2r[r] = s2[b * 4096 + row0 + 8 * w + r];

  float sar[8] = {0.f,0.f,0.f,0.f,0.f,0.f,0.f,0.f};
  f32x4 acc0 = {0.f,0.f,0.f,0.f}, acc1 = {0.f,0.f,0.f,0.f};

  f32x4 aX[8], aY[8], sX, sY;
  u32x4 bv[8];

#define LOADADJ(av, sv, ks) do {                                              \
    const int ko = ((ks) & 15) << 8;                                          \
    _Pragma("unroll")                                                         \
    for (int r = 0; r < 8; ++r)                                               \
      av[r] = *(const f32x4*)(adjW + (size_t)r * 4096 + ko);                  \
    sv = *(const f32x4*)(s1W + ko);                                           \
  } while (0)

#define LOADB(ks) do {                                                        \
    const int ko = ((ks) & 15) << 8;                                          \
    _Pragma("unroll")                                                         \
    for (int kk = 0; kk < 8; ++kk)                                            \
      bv[kk] = *(const u32x4*)(wtB + ko + 32 * kk);                           \
  } while (0)

  // lane l holds rows 8w..8w+7, cols [4l,4l+4). Write 8B to swizzled P row:
  // element col c of row r8 lives at short-offset c ^ ((r8&7)<<3).
#define PBUILD(av, sv, buf) do {                                              \
    unsigned short* Pd = &Pws[buf][0];                                        \
    _Pragma("unroll")                                                         \
    for (int r = 0; r < 8; ++r) {                                             \
      float e0 = s2r[r] + sv[0], e1 = s2r[r] + sv[1];                         \
      float e2 = s2r[r] + sv[2], e3 = s2r[r] + sv[3];                         \
      e0 = fmaxf(e0, 0.2f * e0); e1 = fmaxf(e1, 0.2f * e1);                   \
      e2 = fmaxf(e2, 0.2f * e2); e3 = fmaxf(e3, 0.2f * e3);                   \
      float p0 = vexp2_(e0), p1 = vexp2_(e1);                                 \
      float p2 = vexp2_(e2), p3 = vexp2_(e3);                                 \
      float w0 = av[r][0] * p0, w1 = av[r][1] * p1;                           \
      float w2 = av[r][2] * p2, w3 = av[r][3] * p3;                           \
      sar[r] += (w0 + w1) + (w2 + w3);                                        \
      uint2 pk; pk.x = pk2(w0, w1); pk.y = pk2(w2, w3);                       \
      *(uint2*)(Pd + (8 * w + r) * 256 + ((4 * l) ^ (r << 3))) = pk;          \
    }                                                                         \
  } while (0)

#define SYNC() do {                                                           \
    asm volatile("s_waitcnt lgkmcnt(0)" ::: "memory");                        \
    __builtin_amdgcn_sched_barrier(0);                                        \
    __builtin_amdgcn_s_barrier();                                             \
    __builtin_amdgcn_sched_barrier(0);                                        \
  } while (0)

#define MFMAP(buf) do {                                                       \
    const unsigned short* Pr = &Pws[buf][0];                                  \
    _Pragma("unroll")                                                         \
    for (int kk = 0; kk < 8; ++kk) {                                          \
      const int koff = (8 * g + 32 * kk) ^ ((lr & 7) << 3);                   \
      bf16x8 a0 = *(const bf16x8*)(Pr + lr * 256 + koff);                     \
      bf16x8 a1 = *(const bf16x8*)(Pr + (16 + lr) * 256 + koff);              \
      acc0 = __builtin_amdgcn_mfma_f32_16x16x32_bf16(a0, u2b(bv[kk]), acc0, 0, 0, 0); \
      acc1 = __builtin_amdgcn_mfma_f32_16x16x32_bf16(a1, u2b(bv[kk]), acc1, 0, 0, 0); \
    }                                                                         \
  } while (0)

  LOADADJ(aX, sX, 0);
  LOADADJ(aY, sY, 1);
  LOADB(0);

  for (int it = 0; it < 8; ++it) {
    PBUILD(aX, sX, 0);
    LOADADJ(aX, sX, 2 * it + 2);   // depth-2 HBM prefetch (wraps harmlessly)
    SYNC();                        // lgkm only: HBM prefetch stays in flight
    MFMAP(0);
    LOADB(2 * it + 1);             // B(s+1): in flight across next P-build

    PBUILD(aY, sY, 1);
    LOADADJ(aY, sY, 2 * it + 3);
    SYNC();
    MFMAP(1);
    LOADB(2 * it + 2);
  }

  // S row sums: full-wave butterfly per row, lane 0 publishes
  #pragma unroll
  for (int r = 0; r < 8; ++r) {
    float v = sar[r];
    #pragma unroll
    for (int m = 1; m < 64; m <<= 1) v += __shfl_xor(v, m);
    sar[r] = v;
  }
  if (l == 0) {
    #pragma unroll
    for (int r = 0; r < 8; ++r) Ss[8 * w + r] = sar[r];
  }
  __syncthreads();

  // epilogue: out = acc / S ; C layout col=lr, row=4g+reg (+16 for acc1)
  #pragma unroll
  for (int reg = 0; reg < 4; ++reg) {
    const int r0 = 4 * g + reg, r1 = 16 + 4 * g + reg;
    const float i0 = 1.0f / Ss[r0], i1 = 1.0f / Ss[r1];
    const size_t ob = ((size_t)(b * 4096 + row0 + r0)) * 64 + 16 * w + lr;
    out[ob] = acc0[reg] * i0;
    out[ob + (size_t)16 * 64] = acc1[reg] * i1;
  }
}

extern "C" void kernel_launch(void* const* d_in, const int* in_sizes, int n_in,
                              void* d_out, int out_size, void* d_ws, size_t ws_size,
                              hipStream_t stream) {
  const float* h   = (const float*)d_in[0];
  const float* adj = (const float*)d_in[1];
  const float* W   = (const float*)d_in[2];
  const float* a   = (const float*)d_in[3];
  float* out = (float*)d_out;

  // ws layout: WhT (2MB bf16) | s1 (64KB) | s2 (64KB)
  unsigned short* wt = (unsigned short*)d_ws;
  float* s1 = (float*)(wt + (size_t)4 * 64 * 4096);
  float* s2 = s1 + 16384;

  k_wh  <<<512, 256, 0, stream>>>(h, W, a, wt, s1, s2);
  k_main<<<512, 256, 0, stream>>>(adj, wt, s1, s2, out);
}

// Round 9
// 60.293 us; speedup vs baseline: 2.4243x; 1.1630x over previous
//
#include <hip/hip_runtime.h>
#include <hip/hip_bf16.h>

// GAT layer, B=4, N=4096, F_in=128, F_out=64.
// out_i = sum_j adj_ij * exp(leaky(s2_i+s1_j)) * Wh_j / sum_j adj_ij*exp(..)
// (softmax normalizer cancels; eps*Z term is 2e-9 relative -> dropped;
//  scores O(8) so bare exp2 is safe; s1/s2 pre-scaled by log2 e.)
//
// R9 = R8 + wt stored in MFMA-FRAGMENT ORDER:
//   segment S = (b*128 + k/32)*4 + col/16   (1KB per segment)
//   within S: lane = ((k%32)/8)*16 + col%16 holds 8 shorts (k%8)
// -> each B load in k_main is ONE contiguous 1KB wave-instruction (16 txns
//    vs 64 for the old 4096-stride gather). k_main was L1-transaction-bound
//    on the B gather (R5/R6 scaling evidence); this cuts B txns 4x.

typedef __attribute__((ext_vector_type(8))) short bf16x8;
typedef __attribute__((ext_vector_type(4))) float f32x4;
typedef __attribute__((ext_vector_type(4))) unsigned int u32x4;

#define LOG2E 1.4426950408889634f

__device__ __forceinline__ unsigned int pk2(float lo, float hi) {
  float2 f2; f2.x = lo; f2.y = hi;
  union { __hip_bfloat162 b; unsigned int u; } c;
  c.b = __float22bfloat162_rn(f2);
  return c.u;
}
__device__ __forceinline__ bf16x8 u2b(u32x4 v) {
  union { u32x4 u; bf16x8 b; } c; c.u = v; return c.b;
}
__device__ __forceinline__ float vexp2_(float x) {
  float r; asm("v_exp_f32 %0, %1" : "=v"(r) : "v"(x)); return r;
}

// ---------------- K1: Wh = h @ W (f32); wt bf16 in fragment order;
//                  s1 = Wh a1 * log2e, s2 = Wh a2 * log2e
__global__ __launch_bounds__(256) void k_wh(
    const float* __restrict__ h, const float* __restrict__ W, const float* __restrict__ a,
    unsigned short* __restrict__ wt, float* __restrict__ s1, float* __restrict__ s2) {
  __shared__ float hs[32][130];
  __shared__ float Ws[128 * 64];
  const int t = threadIdx.x;
  const int b = blockIdx.x >> 7;
  const int row0 = (blockIdx.x & 127) << 5;

  // stage W (32KB) into LDS, once
  #pragma unroll
  for (int it = 0; it < 8; ++it) {
    const int fidx = it * 256 + t;
    ((float4*)Ws)[fidx] = ((const float4*)W)[fidx];
  }
  // stage h tile: 32 rows x 128 f32
  #pragma unroll
  for (int it = 0; it < 4; ++it) {
    int flat = it * 256 + t;
    int r = flat >> 5, q = flat & 31;
    const float4 v = *(const float4*)(h + ((size_t)(b * 4096 + row0 + r)) * 128 + 4 * q);
    hs[r][4*q+0] = v.x; hs[r][4*q+1] = v.y; hs[r][4*q+2] = v.z; hs[r][4*q+3] = v.w;
  }
  __syncthreads();

  const int rg = t >> 4, cg = t & 15;
  float acc[2][4] = {};
  for (int k = 0; k < 128; ++k) {
    float4 wv = ((const float4*)Ws)[k * 16 + cg];   // LDS b128, 2-way max
    #pragma unroll
    for (int i = 0; i < 2; ++i) {
      float hv = hs[2*rg + i][k];
      acc[i][0] = fmaf(hv, wv.x, acc[i][0]);
      acc[i][1] = fmaf(hv, wv.y, acc[i][1]);
      acc[i][2] = fmaf(hv, wv.z, acc[i][2]);
      acc[i][3] = fmaf(hv, wv.w, acc[i][3]);
    }
  }
  __syncthreads();

  float (*WhF)[68] = (float(*)[68])hs;
  #pragma unroll
  for (int i = 0; i < 2; ++i)
    #pragma unroll
    for (int j = 0; j < 4; ++j)
      WhF[2*rg + i][4*cg + j] = acc[i][j];
  __syncthreads();

  if (t < 32) {
    float x1 = 0.f, x2 = 0.f;
    #pragma unroll 8
    for (int c = 0; c < 64; ++c) {
      float v = WhF[t][c];
      x1 = fmaf(v, a[c], x1);
      x2 = fmaf(v, a[64 + c], x2);
    }
    s1[b * 4096 + row0 + t] = x1 * LOG2E;
    s2[b * 4096 + row0 + t] = x2 * LOG2E;
  }

  // fragment-order store: this tile covers kk32 = row0>>5 exactly.
  const int col = t >> 2, sub = t & 3;   // sub = (k%32)/8
  unsigned int uh[4];
  #pragma unroll
  for (int r = 0; r < 4; ++r)
    uh[r] = pk2(WhF[8*sub + 2*r][col], WhF[8*sub + 2*r + 1][col]);
  const int S = (b * 128 + (row0 >> 5)) * 4 + (col >> 4);
  unsigned short* dst = wt + ((size_t)S << 9) + sub * 128 + (col & 15) * 8;
  *(uint4*)dst = make_uint4(uh[0], uh[1], uh[2], uh[3]);
}

// ---------------- K3: out = P @ Wh, K-step 256.
// 512 blocks x 256 thr (4 waves, 2 blocks/CU). Wave w owns adj rows 8w..8w+7
// (1KB-contiguous loads) and output cols 16w..16w+16 (B private, contiguous
// 1KB fragment loads). P: registers -> swizzled LDS -> A-frags.
__global__ __launch_bounds__(256, 2) void k_main(
    const float* __restrict__ adj, const unsigned short* __restrict__ wt,
    const float* __restrict__ s1, const float* __restrict__ s2,
    float* __restrict__ out) {
  __shared__ unsigned short Pws[2][8192];   // 2 x (32 rows x 512B, XOR-swizzled)
  __shared__ float Ss[32];

  const int t = threadIdx.x;
  const int blk = blockIdx.x;
  const int xcd = blk & 7;                   // default round-robin XCD id
  const int b = xcd >> 1;                    // one batch per XCD pair: wt L2-resident
  const int tile = (blk >> 3) + ((xcd & 1) << 6);   // 0..127 bijective per b
  const int row0 = tile << 5;
  const int l = t & 63, w = t >> 6;
  const int lr = l & 15, g = l >> 4;

  const float* adjW = adj + ((size_t)(b * 4096 + row0 + 8 * w)) * 4096 + 4 * l;
  const float* s1W  = s1 + b * 4096 + 4 * l;
  // fragment-order B base for this wave: segment (b*128 + kk32)*4 + w
  const unsigned short* wtW = wt + (((size_t)(b * 128) * 4 + w) << 9) + 8 * l;

  float s2r[8];
  #pragma unroll
  for (int r = 0; r < 8; ++r) s2r[r] = s2[b * 4096 + row0 + 8 * w + r];

  float sar[8] = {0.f,0.f,0.f,0.f,0.f,0.f,0.f,0.f};
  f32x4 acc0 = {0.f,0.f,0.f,0.f}, acc1 = {0.f,0.f,0.f,0.f};

  f32x4 aX[8], aY[8], sX, sY;
  u32x4 bv[8];

#define LOADADJ(av, sv, ks) do {                                              \
    const int ko = ((ks) & 15) << 8;                                          \
    _Pragma("unroll")                                                         \
    for (int r = 0; r < 8; ++r)                                               \
      av[r] = *(const f32x4*)(adjW + (size_t)r * 4096 + ko);                  \
    sv = *(const f32x4*)(s1W + ko);                                           \
  } while (0)

  // 8 contiguous 1KB loads: kk32 = ksm*8 + kk, stride 4 segments (2048 shorts)
#define LOADB(ks) do {                                                        \
    const int ksm = (ks) & 15;                                                \
    const unsigned short* bp = wtW + ((size_t)(ksm * 8) << 11);               \
    _Pragma("unroll")                                                         \
    for (int kk = 0; kk < 8; ++kk)                                            \
      bv[kk] = *(const u32x4*)(bp + (kk << 11));                              \
  } while (0)

  // lane l holds rows 8w..8w+7, cols [4l,4l+4). Write 8B to swizzled P row:
  // element col c of row r8 lives at short-offset c ^ ((r8&7)<<3).
#define PBUILD(av, sv, buf) do {                                              \
    unsigned short* Pd = &Pws[buf][0];                                        \
    _Pragma("unroll")                                                         \
    for (int r = 0; r < 8; ++r) {                                             \
      float e0 = s2r[r] + sv[0], e1 = s2r[r] + sv[1];                         \
      float e2 = s2r[r] + sv[2], e3 = s2r[r] + sv[3];                         \
      e0 = fmaxf(e0, 0.2f * e0); e1 = fmaxf(e1, 0.2f * e1);                   \
      e2 = fmaxf(e2, 0.2f * e2); e3 = fmaxf(e3, 0.2f * e3);                   \
      float p0 = vexp2_(e0), p1 = vexp2_(e1);                                 \
      float p2 = vexp2_(e2), p3 = vexp2_(e3);                                 \
      float w0 = av[r][0] * p0, w1 = av[r][1] * p1;                           \
      float w2 = av[r][2] * p2, w3 = av[r][3] * p3;                           \
      sar[r] += (w0 + w1) + (w2 + w3);                                        \
      uint2 pk; pk.x = pk2(w0, w1); pk.y = pk2(w2, w3);                       \
      *(uint2*)(Pd + (8 * w + r) * 256 + ((4 * l) ^ (r << 3))) = pk;          \
    }                                                                         \
  } while (0)

#define SYNC() do {                                                           \
    asm volatile("s_waitcnt lgkmcnt(0)" ::: "memory");                        \
    __builtin_amdgcn_sched_barrier(0);                                        \
    __builtin_amdgcn_s_barrier();                                             \
    __builtin_amdgcn_sched_barrier(0);                                        \
  } while (0)

#define MFMAP(buf) do {                                                       \
    const unsigned short* Pr = &Pws[buf][0];                                  \
    _Pragma("unroll")                                                         \
    for (int kk = 0; kk < 8; ++kk) {                                          \
      const int koff = (8 * g + 32 * kk) ^ ((lr & 7) << 3);                   \
      bf16x8 a0 = *(const bf16x8*)(Pr + lr * 256 + koff);                     \
      bf16x8 a1 = *(const bf16x8*)(Pr + (16 + lr) * 256 + koff);              \
      acc0 = __builtin_amdgcn_mfma_f32_16x16x32_bf16(a0, u2b(bv[kk]), acc0, 0, 0, 0); \
      acc1 = __builtin_amdgcn_mfma_f32_16x16x32_bf16(a1, u2b(bv[kk]), acc1, 0, 0, 0); \
    }                                                                         \
  } while (0)

  LOADADJ(aX, sX, 0);
  LOADADJ(aY, sY, 1);
  LOADB(0);

  for (int it = 0; it < 8; ++it) {
    PBUILD(aX, sX, 0);
    LOADADJ(aX, sX, 2 * it + 2);   // depth-2 HBM prefetch (wraps harmlessly)
    SYNC();                        // lgkm only: HBM prefetch stays in flight
    MFMAP(0);
    LOADB(2 * it + 1);             // B(s+1): in flight across next P-build

    PBUILD(aY, sY, 1);
    LOADADJ(aY, sY, 2 * it + 3);
    SYNC();
    MFMAP(1);
    LOADB(2 * it + 2);
  }

  // S row sums: full-wave butterfly per row, lane 0 publishes
  #pragma unroll
  for (int r = 0; r < 8; ++r) {
    float v = sar[r];
    #pragma unroll
    for (int m = 1; m < 64; m <<= 1) v += __shfl_xor(v, m);
    sar[r] = v;
  }
  if (l == 0) {
    #pragma unroll
    for (int r = 0; r < 8; ++r) Ss[8 * w + r] = sar[r];
  }
  __syncthreads();

  // epilogue: out = acc / S ; C layout col=lr, row=4g+reg (+16 for acc1)
  #pragma unroll
  for (int reg = 0; reg < 4; ++reg) {
    const int r0 = 4 * g + reg, r1 = 16 + 4 * g + reg;
    const float i0 = 1.0f / Ss[r0], i1 = 1.0f / Ss[r1];
    const size_t ob = ((size_t)(b * 4096 + row0 + r0)) * 64 + 16 * w + lr;
    out[ob] = acc0[reg] * i0;
    out[ob + (size_t)16 * 64] = acc1[reg] * i1;
  }
}

extern "C" void kernel_launch(void* const* d_in, const int* in_sizes, int n_in,
                              void* d_out, int out_size, void* d_ws, size_t ws_size,
                              hipStream_t stream) {
  const float* h   = (const float*)d_in[0];
  const float* adj = (const float*)d_in[1];
  const float* W   = (const float*)d_in[2];
  const float* a   = (const float*)d_in[3];
  float* out = (float*)d_out;

  // ws layout: wt (2MB bf16, fragment order) | s1 (64KB) | s2 (64KB)
  unsigned short* wt = (unsigned short*)d_ws;
  float* s1 = (float*)(wt + (size_t)4 * 64 * 4096);
  float* s2 = s1 + 16384;

  k_wh  <<<512, 256, 0, stream>>>(h, W, a, wt, s1, s2);
  k_main<<<512, 256, 0, stream>>>(adj, wt, s1, s2, out);
}